// Round 1
// baseline (262.840 us; speedup 1.0000x reference)
//
#include <hip/hip_runtime.h>
#include <math.h>

// Laplacian-pyramid L1 loss, shape (2,1,64,256,256), 5 levels, sigma=1 (9-tap) scipy-reflect.
// Uses linearity: loss = sum_l mean |lap_pyramid(input - target)[l]|.

struct GW { float w[9]; float A, B; };

__device__ __forceinline__ int ridx(int p, int n) {
    int m = 2 * n;
    int q = p % m;
    if (q < 0) q += m;
    return (q < n) ? q : (m - 1 - q);
}

// K1: fused W+H gaussian on a (H,W) slice, emitting ONLY even (y,x) samples -> (Hd,Wd).
// grid: x tiles of 32 (downsampled cols), y tiles of 8 (downsampled rows), z = B*D slices.
template<bool DIFF>
__global__ __launch_bounds__(256)
void k1_whdown(const float* __restrict__ inA, const float* __restrict__ inB,
               float* __restrict__ out, int H, int W, int Hd, int Wd, GW g)
{
    const int slice = blockIdx.z;
    const int x0 = blockIdx.x * 32;
    const int y0 = blockIdx.y * 8;
    const size_t in_off  = (size_t)slice * H * W;
    const size_t out_off = (size_t)slice * Hd * Wd;
    __shared__ float raw[24][72];   // input rows [2y0-4, 2y0+20), cols [2x0-4, 2x0+68)
    __shared__ float mid[24][32];   // W-filtered at even x
    const int tid = threadIdx.x;
    const bool interior = (2*y0 - 4 >= 0) && (2*y0 + 19 < H) && (2*x0 - 4 >= 0) && (2*x0 + 67 < W);
    for (int i = tid; i < 24*72; i += 256) {
        int rr = i / 72, cc = i - rr*72;
        int gy, gx;
        if (interior) { gy = 2*y0 - 4 + rr; gx = 2*x0 - 4 + cc; }
        else { gy = ridx(2*y0 - 4 + rr, H); gx = ridx(2*x0 - 4 + cc, W); }
        size_t idx = in_off + (size_t)gy * W + gx;
        float v = inA[idx];
        if (DIFF) v -= inB[idx];
        raw[rr][cc] = v;
    }
    __syncthreads();
    for (int i = tid; i < 24*32; i += 256) {
        int rr = i / 32, c = i - rr*32;
        float s = 0.f;
        #pragma unroll
        for (int k = 0; k < 9; ++k) s += g.w[k] * raw[rr][2*c + k];
        mid[rr][c] = s;
    }
    __syncthreads();
    {
        int r = tid >> 5, c = tid & 31;
        int oy = y0 + r, ox = x0 + c;
        if (oy < Hd && ox < Wd) {
            float s = 0.f;
            #pragma unroll
            for (int k = 0; k < 9; ++k) s += g.w[k] * mid[2*r + k][c];
            out[out_off + (size_t)oy * Wd + ox] = s;
        }
    }
}

// K2: D-axis gaussian + batch mix, sampled at even z only -> down (B,Dd,Hd,Wd).
// T1 layout (B, D, M), M = Hd*Wd.
__global__ __launch_bounds__(256)
void k2_dmix_down(const float* __restrict__ T1, float* __restrict__ dn,
                  int D, int Dd, int M, GW g)
{
    long i = (long)blockIdx.x * 256 + threadIdx.x;
    long n = (long)Dd * M;
    if (i >= n) return;
    int zd = (int)(i / M);
    int md = (int)(i - (long)zd * M);
    float s0 = 0.f, s1 = 0.f;
    #pragma unroll
    for (int k = 0; k < 9; ++k) {
        int zk = ridx(2*zd - 4 + k, D);
        s0 += g.w[k] * T1[(size_t)zk * M + md];
        s1 += g.w[k] * T1[(size_t)(D + zk) * M + md];
    }
    dn[(size_t)zd * M + md]        = g.A * s0 + g.B * s1;
    dn[(size_t)(Dd + zd) * M + md] = g.B * s0 + g.A * s1;
}

// K3: D-axis gaussian + batch mix of the zero-stuffed upsample input t (t nonzero at even z),
// over compact (y,x) support. V (B, D, Hd*Wd). Includes the *8 factor.
__global__ __launch_bounds__(256)
void k3_vpass(const float* __restrict__ dn, float* __restrict__ V,
              int D, int Dd, int M, GW g)
{
    long i = (long)blockIdx.x * 256 + threadIdx.x;
    long n = (long)D * M;
    if (i >= n) return;
    int z = (int)(i / M);
    int md = (int)(i - (long)z * M);
    float s0 = 0.f, s1 = 0.f;
    #pragma unroll
    for (int k = 0; k < 9; ++k) {
        int zk = ridx(z - 4 + k, D);
        if ((zk & 1) == 0) {
            int j = zk >> 1;
            s0 += g.w[k] * dn[(size_t)j * M + md];
            s1 += g.w[k] * dn[(size_t)(Dd + j) * M + md];
        }
    }
    V[(size_t)z * M + md]       = 8.f * (g.A * s0 + g.B * s1);
    V[(size_t)(D + z) * M + md] = 8.f * (g.B * s0 + g.A * s1);
}

// K4: finish up = (H-filter with even-y parity) o (W-filter with x<Wd support) of V,
// then accumulate sum |cur - up| (cur = inA or inA-inB), atomicAdd scaled mean into loss.
// grid: x tiles of 64 over W, y tiles of 16 over H, z = B*D slices.
template<bool DIFF>
__global__ __launch_bounds__(256)
void k4_up_reduce(const float* __restrict__ V, const float* __restrict__ curA,
                  const float* __restrict__ curB, float* __restrict__ out_loss,
                  int H, int W, int Hd, int Wd, float inv_numel, GW g)
{
    const int slice = blockIdx.z;
    const int x0 = blockIdx.x * 64;
    const int y0 = blockIdx.y * 16;
    const size_t v_off = (size_t)slice * Hd * Wd;
    const size_t c_off = (size_t)slice * H * W;
    __shared__ float vt[13][72];   // t-space cols tx = x0-4+cc ; V rows vy = y0/2-2+rr
    __shared__ float mid[13][64];  // W-filtered rows (even t-rows), out cols x0..x0+63
    const int tid = threadIdx.x;
    const int vy0 = (y0 >> 1) - 2;
    for (int i = tid; i < 13*72; i += 256) {
        int rr = i / 72, cc = i - rr*72;
        int vy = vy0 + rr;
        int tx = x0 - 4 + cc;
        float v = 0.f;
        if (vy >= 0 && vy < Hd && tx >= 0 && tx < Wd) v = V[v_off + (size_t)vy * Wd + tx];
        vt[rr][cc] = v;
    }
    __syncthreads();
    const bool xin = (x0 - 4 >= 0) && (x0 + 67 < W);
    for (int i = tid; i < 13*64; i += 256) {
        int rr = i / 64, c = i - rr*64;
        float s = 0.f;
        if (xin) {
            #pragma unroll
            for (int k = 0; k < 9; ++k) s += g.w[k] * vt[rr][c + k];
        } else {
            int x = x0 + c;
            #pragma unroll
            for (int k = 0; k < 9; ++k) {
                int gx = ridx(x - 4 + k, W);
                s += g.w[k] * vt[rr][gx - (x0 - 4)];
            }
        }
        mid[rr][c] = s;
    }
    __syncthreads();
    const bool yin = (y0 - 4 >= 0) && (y0 + 19 < H);
    float lsum = 0.f;
    {
        int c = tid & 63;
        int r4 = tid >> 6;
        int ox = x0 + c;
        #pragma unroll
        for (int j = 0; j < 4; ++j) {
            int oy = y0 + r4 * 4 + j;
            if (ox < W && oy < H) {
                float s = 0.f;
                if (yin) {
                    #pragma unroll
                    for (int k = 0; k < 9; ++k) {
                        int gy = oy - 4 + k;
                        if ((gy & 1) == 0) s += g.w[k] * mid[(gy >> 1) - vy0][c];
                    }
                } else {
                    #pragma unroll
                    for (int k = 0; k < 9; ++k) {
                        int gy = ridx(oy - 4 + k, H);
                        if ((gy & 1) == 0) s += g.w[k] * mid[(gy >> 1) - vy0][c];
                    }
                }
                size_t idx = c_off + (size_t)oy * W + ox;
                float cv = curA[idx];
                if (DIFF) cv -= curB[idx];
                lsum += fabsf(cv - s);
            }
        }
    }
    // block reduce: wave shuffle then cross-wave via LDS
    float s = lsum;
    #pragma unroll
    for (int off = 32; off > 0; off >>= 1) s += __shfl_down(s, off, 64);
    __shared__ float wpart[4];
    if ((tid & 63) == 0) wpart[tid >> 6] = s;
    __syncthreads();
    if (tid == 0) {
        atomicAdd(out_loss, (wpart[0] + wpart[1] + wpart[2] + wpart[3]) * inv_numel);
    }
}

extern "C" void kernel_launch(void* const* d_in, const int* in_sizes, int n_in,
                              void* d_out, int out_size, void* d_ws, size_t ws_size,
                              hipStream_t stream)
{
    const float* in = (const float*)d_in[0];
    const float* tg = (const float*)d_in[1];
    float* out = (float*)d_out;

    GW g;
    {
        double u[9], S = 0.0;
        for (int k = 0; k < 9; ++k) { double d = k - 4; u[k] = exp(-0.5 * d * d); S += u[k]; }
        for (int k = 0; k < 9; ++k) g.w[k] = (float)(u[k] / S);
        g.A = (float)((2.0*u[0] + u[1] + u[3] + u[4]) / S);  // batch(n=2) reflect self-weight
        g.B = (float)((u[1] + 2.0*u[2] + u[3]) / S);         // cross-weight
    }

    // workspace layout (floats)
    float* T1 = (float*)d_ws;               // max 2*64*128*128 = 2097152 floats
    float* V  = T1 + 2*64*128*128;          // max 2097152 floats
    float* C1 = V  + 2*64*128*128;          // 2*32*128*128 = 1048576
    float* C2 = C1 + 2*32*128*128;          // 2*16*64*64   = 131072
    float* C3 = C2 + 2*16*64*64;            // 2*8*32*32    = 16384
    float* C4 = C3 + 2*8*32*32;             // 2*4*16*16    = 2048
    float* C5 = C4 + 2*4*16*16;             // 2*2*8*8      = 256
    float* CUR[6] = { nullptr, C1, C2, C3, C4, C5 };

    hipMemsetAsync(out, 0, sizeof(float) * (out_size > 0 ? out_size : 1), stream);

    int D = 64, H = 256, W = 256;
    for (int l = 0; l < 5; ++l) {
        const int Dd = D / 2, Hd = H / 2, Wd = W / 2;
        const int M = Hd * Wd;
        float* dn = CUR[l + 1];

        dim3 blk(256);
        dim3 g1((Wd + 31) / 32, (Hd + 7) / 8, 2 * D);
        if (l == 0) k1_whdown<true ><<<g1, blk, 0, stream>>>(in, tg, T1, H, W, Hd, Wd, g);
        else        k1_whdown<false><<<g1, blk, 0, stream>>>(CUR[l], nullptr, T1, H, W, Hd, Wd, g);

        long n2 = (long)Dd * M;
        k2_dmix_down<<<(unsigned)((n2 + 255) / 256), blk, 0, stream>>>(T1, dn, D, Dd, M, g);

        long n3 = (long)D * M;
        k3_vpass<<<(unsigned)((n3 + 255) / 256), blk, 0, stream>>>(dn, V, D, Dd, M, g);

        dim3 g4((W + 63) / 64, (H + 15) / 16, 2 * D);
        float inv_numel = 1.0f / (float)(2 * D * H * W);
        if (l == 0) k4_up_reduce<true ><<<g4, blk, 0, stream>>>(V, in, tg, out, H, W, Hd, Wd, inv_numel, g);
        else        k4_up_reduce<false><<<g4, blk, 0, stream>>>(V, CUR[l], nullptr, out, H, W, Hd, Wd, inv_numel, g);

        D = Dd; H = Hd; W = Wd;
    }
}

// Round 2
// 162.815 us; speedup vs baseline: 1.6144x; 1.6144x over previous
//
#include <hip/hip_runtime.h>
#include <math.h>

// Laplacian-pyramid L1 loss, shape (2,1,64,256,256), 5 levels, sigma=1 (9-tap) scipy-reflect.
// Uses linearity: loss = sum_l mean |lap_pyramid(input - target)[l]|.
// No global atomics: per-block partials -> final 1-block reduce.

struct GW { float w[9]; float A, B; };

__device__ __forceinline__ int ridx(int p, int n) {
    // n is a power of two here; scipy 'reflect' (symmetric) index
    int m = 2 * n;
    int q = (p + m) & (m - 1);
    return (q < n) ? q : (m - 1 - q);
}

__device__ __forceinline__ void fma4(float4& a, float w, const float4 b) {
    a.x = fmaf(w, b.x, a.x); a.y = fmaf(w, b.y, a.y);
    a.z = fmaf(w, b.z, a.z); a.w = fmaf(w, b.w, a.w);
}

__device__ __forceinline__ float block_sum256(float v) {
    #pragma unroll
    for (int off = 32; off > 0; off >>= 1) v += __shfl_down(v, off, 64);
    __shared__ float wp[4];
    int tid = threadIdx.x;
    if ((tid & 63) == 0) wp[tid >> 6] = v;
    __syncthreads();
    return wp[0] + wp[1] + wp[2] + wp[3];
}

// ---------------------------------------------------------------------------
// K1: fused W+H gaussian on (H,W) slices, emitting ONLY even (y,x) -> (Hd,Wd).
// Tile: 64 wide x 16 high in downsampled space. grid z = B*D slices.
template<bool DIFF>
__global__ __launch_bounds__(256)
void k1_whdown(const float* __restrict__ inA, const float* __restrict__ inB,
               float* __restrict__ out, int H, int W, int Hd, int Wd, GW g)
{
    const int slice = blockIdx.z;
    const int x0d = blockIdx.x * 64;
    const int y0d = blockIdx.y * 16;
    const size_t in_off  = (size_t)slice * H * W;
    const size_t out_off = (size_t)slice * Hd * Wd;
    __shared__ float raw[40][136];  // input rows [2y0d-4, 2y0d+36), cols [2x0d-4, 2x0d+132)
    __shared__ float mid[40][64];   // W-filtered at even x
    const int tid = threadIdx.x;
    const bool interior = (2*y0d - 4 >= 0) && (2*y0d + 35 < H) &&
                          (2*x0d - 4 >= 0) && (2*x0d + 131 < W);
    for (int i = tid; i < 40*136; i += 256) {
        int rr = i / 136, cc = i - rr*136;
        int gy, gx;
        if (interior) { gy = 2*y0d - 4 + rr; gx = 2*x0d - 4 + cc; }
        else { gy = ridx(2*y0d - 4 + rr, H); gx = ridx(2*x0d - 4 + cc, W); }
        size_t idx = in_off + (size_t)gy * W + gx;
        float v = inA[idx];
        if (DIFF) v -= inB[idx];
        raw[rr][cc] = v;
    }
    __syncthreads();
    for (int i = tid; i < 40*64; i += 256) {
        int rr = i >> 6, c = i & 63;
        float s = 0.f;
        #pragma unroll
        for (int k = 0; k < 9; ++k) s = fmaf(g.w[k], raw[rr][2*c + k], s);
        mid[rr][c] = s;
    }
    __syncthreads();
    {
        int r = tid >> 6, c = tid & 63;
        int ox = x0d + c;
        #pragma unroll
        for (int j = 0; j < 4; ++j) {
            int oy = y0d + r * 4 + j;
            if (oy < Hd && ox < Wd) {
                int rb = 2 * (oy - y0d);
                float s = 0.f;
                #pragma unroll
                for (int k = 0; k < 9; ++k) s = fmaf(g.w[k], mid[rb + k][c], s);
                out[out_off + (size_t)oy * Wd + ox] = s;
            }
        }
    }
}

// ---------------------------------------------------------------------------
// K2: D-axis gaussian + batch(2) reflect mix, sampled at even z -> down. float4.
__global__ __launch_bounds__(256)
void k2_dmix_down(const float* __restrict__ T1, float* __restrict__ dn,
                  int D, int Dd, int M4, GW g)
{
    long i = (long)blockIdx.x * 256 + threadIdx.x;
    if (i >= (long)Dd * M4) return;
    int zd = (int)(i / M4);
    int q  = (int)(i - (long)zd * M4);
    const float4* T = (const float4*)T1;
    float4* O = (float4*)dn;
    float4 s0 = {0,0,0,0}, s1 = {0,0,0,0};
    if (2*zd - 4 >= 0 && 2*zd + 4 < D) {
        #pragma unroll
        for (int k = 0; k < 9; ++k) {
            int zk = 2*zd - 4 + k;
            fma4(s0, g.w[k], T[(size_t)zk * M4 + q]);
            fma4(s1, g.w[k], T[(size_t)(D + zk) * M4 + q]);
        }
    } else {
        #pragma unroll
        for (int k = 0; k < 9; ++k) {
            int zk = ridx(2*zd - 4 + k, D);
            fma4(s0, g.w[k], T[(size_t)zk * M4 + q]);
            fma4(s1, g.w[k], T[(size_t)(D + zk) * M4 + q]);
        }
    }
    float4 o0, o1;
    o0.x = g.A*s0.x + g.B*s1.x; o0.y = g.A*s0.y + g.B*s1.y;
    o0.z = g.A*s0.z + g.B*s1.z; o0.w = g.A*s0.w + g.B*s1.w;
    o1.x = g.B*s0.x + g.A*s1.x; o1.y = g.B*s0.y + g.A*s1.y;
    o1.z = g.B*s0.z + g.A*s1.z; o1.w = g.B*s0.w + g.A*s1.w;
    O[(size_t)zd * M4 + q] = o0;
    O[(size_t)(Dd + zd) * M4 + q] = o1;
}

// ---------------------------------------------------------------------------
// K3: D-filter of zero-stuffed dn + batch mix (the D,batch part of upsample). float4.
// Parity-split taps: z even -> 5 taps (w0,w2,w4,w6,w8); z odd -> 4 taps (w1,w3,w5,w7).
__global__ __launch_bounds__(256)
void k3_vpass(const float* __restrict__ dn, float* __restrict__ V,
              int D, int Dd, int M4, GW g)
{
    long i = (long)blockIdx.x * 256 + threadIdx.x;
    if (i >= (long)D * M4) return;
    int z = (int)(i / M4);
    int q = (int)(i - (long)z * M4);
    const float4* Dn = (const float4*)dn;
    float4* O = (float4*)V;
    float4 s0 = {0,0,0,0}, s1 = {0,0,0,0};
    if (z >= 4 && z + 4 < D) {
        if ((z & 1) == 0) {
            int base = (z >> 1) - 2;
            #pragma unroll
            for (int kk = 0; kk < 5; ++kk) {
                fma4(s0, g.w[2*kk], Dn[(size_t)(base + kk) * M4 + q]);
                fma4(s1, g.w[2*kk], Dn[(size_t)(Dd + base + kk) * M4 + q]);
            }
        } else {
            int base = (z - 3) >> 1;
            #pragma unroll
            for (int kk = 0; kk < 4; ++kk) {
                fma4(s0, g.w[2*kk+1], Dn[(size_t)(base + kk) * M4 + q]);
                fma4(s1, g.w[2*kk+1], Dn[(size_t)(Dd + base + kk) * M4 + q]);
            }
        }
    } else {
        #pragma unroll
        for (int k = 0; k < 9; ++k) {
            int zk = ridx(z - 4 + k, D);
            if ((zk & 1) == 0) {
                int j = zk >> 1;
                fma4(s0, g.w[k], Dn[(size_t)j * M4 + q]);
                fma4(s1, g.w[k], Dn[(size_t)(Dd + j) * M4 + q]);
            }
        }
    }
    float4 o0, o1;
    o0.x = 8.f*(g.A*s0.x + g.B*s1.x); o0.y = 8.f*(g.A*s0.y + g.B*s1.y);
    o0.z = 8.f*(g.A*s0.z + g.B*s1.z); o0.w = 8.f*(g.A*s0.w + g.B*s1.w);
    o1.x = 8.f*(g.B*s0.x + g.A*s1.x); o1.y = 8.f*(g.B*s0.y + g.A*s1.y);
    o1.z = 8.f*(g.B*s0.z + g.A*s1.z); o1.w = 8.f*(g.B*s0.w + g.A*s1.w);
    O[(size_t)z * M4 + q] = o0;
    O[(size_t)(D + z) * M4 + q] = o1;
}

// ---------------------------------------------------------------------------
// K4: finish up = H-filter (even-row parity) o W-filter (x<Wd support) of V,
// accumulate |cur - up|, write ONE partial per block (scaled by inv_numel).
// Tile: 64 wide x 32 high outputs. grid z = B*D slices.
template<bool DIFF>
__global__ __launch_bounds__(256)
void k4_up_reduce(const float* __restrict__ V, const float* __restrict__ curA,
                  const float* __restrict__ curB, float* __restrict__ partials,
                  int H, int W, int Hd, int Wd, float inv_numel, GW g)
{
    const int slice = blockIdx.z;
    const int x0 = blockIdx.x * 64;
    const int y0 = blockIdx.y * 32;
    const size_t v_off = (size_t)slice * Hd * Wd;
    const size_t c_off = (size_t)slice * H * W;
    __shared__ float vt[20][72];   // V rows [y0/2-2, y0/2+18), t-cols [x0-4, x0+68)
    __shared__ float mid[20][64];  // W-filtered
    const int tid = threadIdx.x;
    const int vy0 = (y0 >> 1) - 2;
    for (int i = tid; i < 20*72; i += 256) {
        int rr = i / 72, cc = i - rr*72;
        int vy = vy0 + rr;
        int tx = x0 - 4 + cc;
        if (tx < 0) tx = -1 - tx;      // left-edge reflect lands in [0,3] < Wd
        float v = 0.f;
        if (vy >= 0 && vy < Hd && tx < Wd) v = V[v_off + (size_t)vy * Wd + tx];
        vt[rr][cc] = v;                // right-edge reflect lands in zero half: 0 either way
    }
    __syncthreads();
    for (int i = tid; i < 20*64; i += 256) {
        int rr = i >> 6, c = i & 63;
        float s = 0.f;
        #pragma unroll
        for (int k = 0; k < 9; ++k) s = fmaf(g.w[k], vt[rr][c + k], s);
        mid[rr][c] = s;
    }
    __syncthreads();
    const bool yin = (y0 >= 4) && (y0 + 35 < H);
    const int c = tid & 63;
    const int ry_base = (tid >> 6) * 8;
    const int ox = x0 + c;
    float lsum = 0.f;
    #pragma unroll
    for (int j = 0; j < 8; ++j) {
        int ry = ry_base + j;          // parity(ry) == parity(j), compile-time per j
        int oy = y0 + ry;
        if (ox < W && oy < H) {
            float s = 0.f;
            if (yin) {
                if ((j & 1) == 0) {
                    int r0 = ry >> 1;  // 5 even taps
                    s = g.w[0]*mid[r0][c] + g.w[2]*mid[r0+1][c] + g.w[4]*mid[r0+2][c]
                      + g.w[6]*mid[r0+3][c] + g.w[8]*mid[r0+4][c];
                } else {
                    int r0 = ((ry - 3) >> 1) + 2;  // 4 odd taps
                    s = g.w[1]*mid[r0][c] + g.w[3]*mid[r0+1][c]
                      + g.w[5]*mid[r0+2][c] + g.w[7]*mid[r0+3][c];
                }
            } else {
                #pragma unroll
                for (int k = 0; k < 9; ++k) {
                    int gy = ridx(oy - 4 + k, H);
                    if ((gy & 1) == 0) s = fmaf(g.w[k], mid[(gy >> 1) - vy0][c], s);
                }
            }
            size_t idx = c_off + (size_t)oy * W + ox;
            float cv = curA[idx];
            if (DIFF) cv -= curB[idx];
            lsum += fabsf(cv - s);
        }
    }
    float tot = block_sum256(lsum);
    if (tid == 0) {
        int bflat = blockIdx.x + gridDim.x * (blockIdx.y + gridDim.y * blockIdx.z);
        partials[bflat] = tot * inv_numel;
    }
}

// ---------------------------------------------------------------------------
__global__ __launch_bounds__(256)
void kreduce(const float* __restrict__ P, int n, float* __restrict__ out)
{
    float s = 0.f;
    for (int i = threadIdx.x; i < n; i += 256) s += P[i];
    float t = block_sum256(s);
    if (threadIdx.x == 0) out[0] = t;
}

// ---------------------------------------------------------------------------
extern "C" void kernel_launch(void* const* d_in, const int* in_sizes, int n_in,
                              void* d_out, int out_size, void* d_ws, size_t ws_size,
                              hipStream_t stream)
{
    const float* in = (const float*)d_in[0];
    const float* tg = (const float*)d_in[1];
    float* out = (float*)d_out;

    GW g;
    {
        double u[9], S = 0.0;
        for (int k = 0; k < 9; ++k) { double d = k - 4; u[k] = exp(-0.5 * d * d); S += u[k]; }
        for (int k = 0; k < 9; ++k) g.w[k] = (float)(u[k] / S);
        g.A = (float)((2.0*u[0] + u[1] + u[3] + u[4]) / S);  // batch(n=2) reflect self-weight
        g.B = (float)((u[1] + 2.0*u[2] + u[3]) / S);         // cross-weight
    }

    // workspace layout (floats)
    float* T1 = (float*)d_ws;               // 2*64*128*128 = 2097152
    float* V  = T1 + 2*64*128*128;          // 2097152
    float* C1 = V  + 2*64*128*128;          // 2*32*128*128 = 1048576
    float* C2 = C1 + 2*32*128*128;          // 2*16*64*64   = 131072
    float* C3 = C2 + 2*16*64*64;            // 2*8*32*32    = 16384
    float* C4 = C3 + 2*8*32*32;             // 2*4*16*16    = 2048
    float* C5 = C4 + 2*4*16*16;             // 2*2*8*8      = 256
    float* P  = C5 + 2*2*8*8;               // partials (4696)
    float* CUR[6] = { nullptr, C1, C2, C3, C4, C5 };

    int D = 64, H = 256, W = 256;
    int np = 0;
    for (int l = 0; l < 5; ++l) {
        const int Dd = D / 2, Hd = H / 2, Wd = W / 2;
        const int M = Hd * Wd, M4 = M / 4;
        float* dn = CUR[l + 1];
        dim3 blk(256);

        dim3 g1((Wd + 63) / 64, (Hd + 15) / 16, 2 * D);
        if (l == 0) k1_whdown<true ><<<g1, blk, 0, stream>>>(in, tg, T1, H, W, Hd, Wd, g);
        else        k1_whdown<false><<<g1, blk, 0, stream>>>(CUR[l], nullptr, T1, H, W, Hd, Wd, g);

        long n2 = (long)Dd * M4;
        k2_dmix_down<<<(unsigned)((n2 + 255) / 256), blk, 0, stream>>>(T1, dn, D, Dd, M4, g);

        long n3 = (long)D * M4;
        k3_vpass<<<(unsigned)((n3 + 255) / 256), blk, 0, stream>>>(dn, V, D, Dd, M4, g);

        dim3 g4((W + 63) / 64, (H + 31) / 32, 2 * D);
        float inv_numel = 1.0f / (float)(2 * D * H * W);
        if (l == 0) k4_up_reduce<true ><<<g4, blk, 0, stream>>>(V, in, tg, P + np, H, W, Hd, Wd, inv_numel, g);
        else        k4_up_reduce<false><<<g4, blk, 0, stream>>>(V, CUR[l], nullptr, P + np, H, W, Hd, Wd, inv_numel, g);
        np += (int)(g4.x * g4.y * g4.z);

        D = Dd; H = Hd; W = Wd;
    }

    kreduce<<<1, 256, 0, stream>>>(P, np, out);
}